// Round 2
// baseline (7722.720 us; speedup 1.0000x reference)
//
#include <hip/hip_runtime.h>

typedef __attribute__((ext_vector_type(8))) short bf16x8;
typedef __attribute__((ext_vector_type(4))) float f32x4;
typedef __attribute__((ext_vector_type(4))) int i32x4;

#define Tn 1024
#define Bn 64
#define Hn 2048
#define NBLK 128
#define NTHR 512

// Dataflow ready counters: one line per (consumer-leaf, K-slice-group).
// 16 leaves x 8 groups = 128 counters, each on its own 128B line (16 KB ctrl).
// Replica (leaf, g) is bumped once per step by each of the 16 producer blocks
// of group g (blocks bid>>4 == g); value == 16*(t+1) means h_{t+1}'s slice g
// is fully at MALL. Consumers of leaf L = blocks [8L, 8L+8): wave w polls
// (L, w) only -> 8 pollers/line (R12 lesson: >100 RMW pollers on ONE line
// serialize, so replicate per leaf).
#define GRP(leaf, g) ((((leaf) << 3) | (g)) * 32)

// watchdog: bounded spin so a liveness bug degrades to a wrong answer
// (diagnosable absmax failure) instead of a container-killing hang
#define SPIN_LIMIT (1u << 25)

__device__ __forceinline__ unsigned short f2b(float x) {
    // fp32 -> bf16 round-to-nearest-even
    unsigned u = __float_as_uint(x);
    return (unsigned short)((u + 0x7fffu + ((u >> 16) & 1u)) >> 16);
}
__device__ __forceinline__ float sigm(float x) {
    return __builtin_amdgcn_rcpf(1.0f + __expf(-x));
}
__device__ __forceinline__ float tanh_f(float x) {
    float e = __expf(2.0f * x);
    return 1.0f - 2.0f * __builtin_amdgcn_rcpf(1.0f + e);
}

// write-through system-scope stores: at MALL once vmcnt retires
__device__ __forceinline__ void store_short_wt(unsigned short* p, unsigned v) {
    asm volatile("global_store_short %0, %1, off sc0 sc1" :: "v"(p), "v"(v) : "memory");
}
__device__ __forceinline__ void store_dword_wt(float* p, float v) {
    asm volatile("global_store_dword %0, %1, off sc0 sc1" :: "v"(p), "v"(__float_as_uint(v)) : "memory");
}
__device__ __forceinline__ void store_u64_wt(unsigned long long* p, unsigned long long v) {
    asm volatile("global_store_dwordx2 %0, %1, off sc0 sc1" :: "v"(p), "v"(v) : "memory");
}
// Poll via atomic RMW(+0): the ONLY read primitive proven promptly coherent
// cross-XCD for ATOMICALLY-updated lines (R1-R6 ablation). asm because
// InstCombine turns fetch_add(p,0) back into a plain atomic load.
__device__ __forceinline__ unsigned poll_read(unsigned* p) {
    unsigned old;
    asm volatile("global_atomic_add %0, %1, %2, off sc0 sc1\n\ts_waitcnt vmcnt(0)"
                 : "=v"(old) : "v"(p), "v"(0u) : "memory");
    return old;
}

// h fragment layout: h_f[kk][mt][laneF][e], kk=k>>5, mt=b>>4,
// laneF=((k>>3)&3)*16+(b&15), e=k&7. One MFMA A-frag = 64 lanes x 16B contig.
__device__ __forceinline__ long hfrag_off(int b, int k) {
    return ((long)(((k >> 5) * 4 + (b >> 4)) * 64) + ((k >> 3) & 3) * 16 + (b & 15)) * 8 + (k & 7);
}

// Prep: init_hidden fp32 -> bf16 h0 (frag layout, WT stores so the MALL copy
// is authoritative for gru's bypass loads); zero ready counters (WT too).
__global__ void prep_kernel(const float* __restrict__ init_h,
                            unsigned short* __restrict__ h0,
                            unsigned* __restrict__ ctrl) {
    const int i = blockIdx.x * 256 + threadIdx.x;  // 0..32767
    const int b  = i >> 9;
    const int k4 = (i & 511) << 2;
    float4 v = *reinterpret_cast<const float4*>(init_h + (long)b * Hn + k4);
    unsigned long long q = (unsigned long long)f2b(v.x)
                         | ((unsigned long long)f2b(v.y) << 16)
                         | ((unsigned long long)f2b(v.z) << 32)
                         | ((unsigned long long)f2b(v.w) << 48);
    store_u64_wt((unsigned long long*)(h0 + hfrag_off(b, k4)), q);
    if (i < 4096)
        asm volatile("global_store_dword %0, %1, off sc0 sc1"
                     :: "v"(ctrl + i), "v"(0u) : "memory");
}

// Persistent GRU. 128 blocks x 512 threads (8 waves).
// Block bk owns 16 hidden units j in [16*bk, 16*bk+16).
// Wave w owns K-slice [256w, 256w+256); W rows live in REGISTERS (Bf[3][8]).
//
// R13: per-K-slice dataflow flags replaced the grid barrier (-11%).
// R14 changes (latency trims, protocol untouched):
//  (1) inp prefetch: x-row for step t+1 is loaded AFTER the MFMA bursts (its
//      HBM RTT hides under reduce+epilogue+drain) and consumed next step.
//      Previously the cold x loads sat BEFORE the poll, whose internal
//      vmcnt(0) drained them -> ~0.3-0.4us of HBM latency serialized into
//      the per-step critical chain. Placement after the last counted-wait
//      asm keeps every s_waitcnt at vmcnt(0) (no count-constant hazards);
//      memory-clobbered asm above / __syncthreads below pin the issue slot.
//  (2) sync2 removed: round-1-add has wave w READ bucket w only; round-2 has
//      wave w WRITE bucket w only -> wave-local program order suffices;
//      cross-wave readers of bucket w only run after sync3.
//  (3) loop-end sync removed: sync4 already orders round-2 reads before any
//      next-iteration LDS write; 7 of 8 waves enter the next poll immediately.
//
// Buffer-reuse safety (unchanged from R13): a block stores h_{t+2} only after
// its 8 waves saw all counters at 16(t+1), i.e. after EVERY block stored
// h_{t+1}, which (program order + drain) is after that block finished READING
// h_t -> the double buffer never races. Skew < 2 steps, deadlock-free.
//
// K-loop: 2 ASM-PINNED bursts of 16x global_load_dwordx4 sc0/sc1, each
// followed by a single s_waitcnt vmcnt(0) carrying the 16 buffers as "+v"
// operands (dataflow ties the MFMAs to the waitcnt -> no hoist hazard).
// NOTE: merging the bursts (one fewer serial MALL RTT) needs 32 live x4
// buffers = +64 VGPRs; Bf(96)+acc(48)+hb(64)+state already sits at the
// 256-unified-reg ceiling for 2 waves/SIMD -> would spill hot regs. Needs a
// 4-wave/512-reg restructure, not attempted here.
// TWO-ROUND LDS reduction (48 KB; >64 KB static LDS kills launch, R7/R8).
// NO fences / NO cache maintenance anywhere in the hot loop (R5 lesson).
// All signals via RMW, all polls via RMW(+0).
__global__ void __launch_bounds__(NTHR, 2) gru_kernel(
    const float* __restrict__ inp,     // [T][B][3]
    const float* __restrict__ init_h,  // [B][H]
    const float* __restrict__ w_ih,    // [3H][3]
    const float* __restrict__ w_hh,    // [3H][H] fp32
    const float* __restrict__ bias,    // [3H]
    const float* __restrict__ bias_n,  // [H]
    unsigned short* __restrict__ h0,   // [B][H] bf16 frag-layout double buffer
    unsigned short* __restrict__ h1,
    unsigned* __restrict__ ctrl,       // [4096] ready counters (128 lines)
    float* __restrict__ out)           // [T][B]
{
    __shared__ f32x4 red[4][4][3][64];  // [bucket][mt][nt][lane] = 48 KB

    const int tid  = threadIdx.x;
    const int lane = tid & 63;
    const int w    = tid >> 6;      // wave id = K-slice owner
    const int quad = lane >> 4;
    const int n16  = lane & 15;
    const int j0   = blockIdx.x * 16;
    const int jg   = j0 + n16;      // this lane's hidden column (epilogue)
    const int ks   = w * 256;

    // ---- preload W rows into registers as bf16 B-fragments (one-time) ----
    bf16x8 Bf[3][8];
    #pragma unroll
    for (int nt = 0; nt < 3; ++nt) {
        const long row = (long)(nt * Hn + j0 + n16);
        #pragma unroll
        for (int k = 0; k < 8; ++k) {
            const float* p = w_hh + row * Hn + ks + k * 32 + quad * 8;
            bf16x8 b;
            #pragma unroll
            for (int j = 0; j < 8; ++j) b[j] = (short)f2b(p[j]);
            Bf[nt][k] = b;
        }
    }

    // Epilogue constants (used by waves 0-3; all 64 lanes active)
    float wr0 = w_ih[jg*3+0], wr1 = w_ih[jg*3+1], wr2 = w_ih[jg*3+2];
    float wz0 = w_ih[(Hn+jg)*3+0], wz1 = w_ih[(Hn+jg)*3+1], wz2 = w_ih[(Hn+jg)*3+2];
    float wn0 = w_ih[(2*Hn+jg)*3+0], wn1 = w_ih[(2*Hn+jg)*3+1], wn2 = w_ih[(2*Hn+jg)*3+2];
    float br_ = bias[jg], bz_ = bias[Hn+jg], bn2_ = bias[2*Hn+jg];
    float bnn_ = bias_n[jg];

    // fp32 hidden state (waves 0-3; batch b = 16*w + quad*4 + r, col jg)
    float hst[4];
    if (w < 4) {
        #pragma unroll
        for (int r = 0; r < 4; ++r)
            hst[r] = init_h[(long)(16 * w + quad * 4 + r) * Hn + jg];
    }

    // x-row for t=0 (prefetched; steady-state loads happen mid-step)
    float xv[4][3];
    if (w < 4) {
        #pragma unroll
        for (int r = 0; r < 4; ++r) {
            const float* xp = inp + ((long)(16 * w + quad * 4 + r)) * 3;
            xv[r][0] = xp[0]; xv[r][1] = xp[1]; xv[r][2] = xp[2];
        }
    }

    // epilogue frag-store decomposition of j = 16*bid + n16
    const int kkE = blockIdx.x >> 1;            // j>>5 (lane-uniform)
    const int qE  = (blockIdx.x & 1) * 2 + (n16 >> 3);
    const int eE  = n16 & 7;

    const int leafC = blockIdx.x >> 3;          // consumer replica index
    const int grp   = blockIdx.x >> 4;          // K-slice group we produce

    for (int t = 0; t < Tn; ++t) {
        const unsigned short* hcur = (t & 1) ? h1 : h0;
        unsigned short* hnext      = (t & 1) ? h0 : h1;

        f32x4 acc[4][3];
        #pragma unroll
        for (int mt = 0; mt < 4; ++mt)
            #pragma unroll
            for (int nt = 0; nt < 3; ++nt)
                acc[mt][nt] = f32x4{0.f, 0.f, 0.f, 0.f};

        // ---- dataflow wait: THIS wave's K-slice fully at MALL? ----
        // lane 0 spins, wave reconverges; volatile-asm ordering keeps the
        // h-burst loads below from hoisting above the poll.
        if (lane == 0 && t) {
            const unsigned tgt = (unsigned)(t << 4);   // 16*t
            unsigned spins = 0;
            while (poll_read(&ctrl[GRP(leafC, w)]) < tgt) {
                __builtin_amdgcn_s_sleep(1);
                if (++spins > SPIN_LIMIT) break;   // watchdog
            }
        }

        // wave's A-frag base: frag f=(k*4+mt) at short-offset f*512 + lane*8
        const unsigned short* pa = hcur + (long)(w * 8 * 4 * 64 + lane) * 8;

        // ---- 2 asm-pinned bursts: 16x dwordx4 loads, waitcnt, 48 MFMAs ----
        i32x4 hb[16];
        #pragma unroll
        for (int half = 0; half < 2; ++half) {
            const unsigned short* ph = pa + (long)(half * 16) * 512;
            #pragma unroll
            for (int f = 0; f < 16; ++f) {
                asm volatile("global_load_dwordx4 %0, %1, off sc0 sc1"
                             : "=v"(hb[f]) : "v"(ph + (long)f * 512) : "memory");
            }
            asm volatile("s_waitcnt vmcnt(0)"
                         : "+v"(hb[0]), "+v"(hb[1]), "+v"(hb[2]), "+v"(hb[3]),
                           "+v"(hb[4]), "+v"(hb[5]), "+v"(hb[6]), "+v"(hb[7]),
                           "+v"(hb[8]), "+v"(hb[9]), "+v"(hb[10]), "+v"(hb[11]),
                           "+v"(hb[12]), "+v"(hb[13]), "+v"(hb[14]), "+v"(hb[15])
                         :: "memory");
            #pragma unroll
            for (int k4i = 0; k4i < 4; ++k4i) {
                const int k = half * 4 + k4i;
                #pragma unroll
                for (int mt = 0; mt < 4; ++mt) {
                    union { i32x4 q; bf16x8 v; } u;
                    u.q = hb[k4i * 4 + mt];
                    bf16x8 a = u.v;
                    acc[mt][0] = __builtin_amdgcn_mfma_f32_16x16x32_bf16(a, Bf[0][k], acc[mt][0], 0, 0, 0);
                    acc[mt][1] = __builtin_amdgcn_mfma_f32_16x16x32_bf16(a, Bf[1][k], acc[mt][1], 0, 0, 0);
                    acc[mt][2] = __builtin_amdgcn_mfma_f32_16x16x32_bf16(a, Bf[2][k], acc[mt][2], 0, 0, 0);
                }
            }
        }

        // ---- prefetch next step's x-row: HBM RTT hides under the LDS
        // reduction + epilogue + drain below; consumed next iteration.
        // (Issued here so every counted wait above stays at vmcnt(0); the
        // drain before sync4 absorbs any residual latency off-path.)
        float xn[4][3];
        if (w < 4) {
            const int tn = (t + 1 < Tn) ? t + 1 : t;
            #pragma unroll
            for (int r = 0; r < 4; ++r) {
                const float* xp = inp + ((long)tn * Bn + 16 * w + quad * 4 + r) * 3;
                xn[r][0] = xp[0]; xn[r][1] = xp[1]; xn[r][2] = xp[2];
            }
        }

        // ---- two-round cross-wave K reduction through LDS (48 KB) ----
        // Round 1: waves 4-7 publish partials into bucket (w-4).
        if (w >= 4) {
            #pragma unroll
            for (int mt = 0; mt < 4; ++mt)
                #pragma unroll
                for (int nt = 0; nt < 3; ++nt)
                    red[w - 4][mt][nt][lane] = acc[mt][nt];
        }
        __syncthreads();   // sync1
        // Round-1 add + round-2 publish: wave w READS bucket w then WRITES
        // bucket w -- wave-local, so NO barrier needed in between (the old
        // sync2 protected disjoint addresses). Cross-wave readers of bucket
        // w run only after sync3.
        if (w < 4) {
            #pragma unroll
            for (int mt = 0; mt < 4; ++mt)
                #pragma unroll
                for (int nt = 0; nt < 3; ++nt) {
                    acc[mt][nt] += red[w][mt][nt][lane];
                    red[w][mt][nt][lane] = acc[mt][nt];
                }
        }
        __syncthreads();   // sync3

        if (w < 4) {
            f32x4 s0 = red[0][w][0][lane], s1 = red[0][w][1][lane], s2 = red[0][w][2][lane];
            #pragma unroll
            for (int src = 1; src < 4; ++src) {
                s0 += red[src][w][0][lane];
                s1 += red[src][w][1][lane];
                s2 += red[src][w][2][lane];
            }
            #pragma unroll
            for (int r = 0; r < 4; ++r) {
                const int b = 16 * w + quad * 4 + r;
                float pr = br_ + wr0*xv[r][0] + wr1*xv[r][1] + wr2*xv[r][2] + s0[r];
                float pz = bz_ + wz0*xv[r][0] + wz1*xv[r][1] + wz2*xv[r][2] + s1[r];
                float rr = sigm(pr);
                float zz = sigm(pz);
                float pn = bn2_ + wn0*xv[r][0] + wn1*xv[r][1] + wn2*xv[r][2] + rr * (s2[r] + bnn_);
                float nn = tanh_f(pn);
                float hv = nn + zz * (hst[r] - nn);
                hst[r] = hv;
                store_short_wt(hnext + ((long)((kkE * 4 + w) * 64) + qE * 16 + quad * 4 + r) * 8 + eE,
                               (unsigned)f2b(hv));
                if (blockIdx.x == 0 && n16 == 0)
                    store_dword_wt(out + t * Bn + b, hv);
            }
            // rotate the x prefetch into place for the next step
            #pragma unroll
            for (int r = 0; r < 4; ++r) {
                xv[r][0] = xn[r][0]; xv[r][1] = xn[r][1]; xv[r][2] = xn[r][2];
            }
        }

        // ---- producer signal: drain WT stores, then bump all 16 leaf
        // replicas of our group's counter (16 lanes, one atomic instr,
        // 16 distinct lines -> no single-line arrival serialization) ----
        asm volatile("s_waitcnt vmcnt(0)" ::: "memory");  // belt-and-braces drain
        __syncthreads();   // sync4: all waves' stores at MALL; fences LDS reuse
        if (tid < 16)
            __hip_atomic_fetch_add(&ctrl[GRP(tid, grp)], 1u,
                                   __ATOMIC_RELAXED, __HIP_MEMORY_SCOPE_SYSTEM);
        // no loop-end barrier: sync4 already orders round-2 reads before any
        // next-iteration LDS write; waves 1-7 head straight into their polls.
    }
}

extern "C" void kernel_launch(void* const* d_in, const int* in_sizes, int n_in,
                              void* d_out, int out_size, void* d_ws, size_t ws_size,
                              hipStream_t stream) {
    const float* inp    = (const float*)d_in[0];  // [1024][64][3]
    const float* init_h = (const float*)d_in[1];  // [64][2048]
    const float* w_ih   = (const float*)d_in[2];  // [6144][3]
    const float* w_hh   = (const float*)d_in[3];  // [6144][2048]
    const float* bias   = (const float*)d_in[4];  // [6144]
    const float* bias_n = (const float*)d_in[5];  // [2048]
    float* out = (float*)d_out;                   // [1024][64]

    unsigned short* h0 = (unsigned short*)d_ws;          // 262144 B
    unsigned short* h1 = h0 + 131072L;                   // 262144 B
    unsigned* ctrl     = (unsigned*)(h1 + 131072L);      // 16384 B

    prep_kernel<<<128, 256, 0, stream>>>(init_h, h0, ctrl);
    gru_kernel<<<NBLK, NTHR, 0, stream>>>(inp, init_h, w_ih, w_hh, bias, bias_n,
                                          h0, h1, ctrl, out);
}

// Round 3
// 5612.642 us; speedup vs baseline: 1.3760x; 1.3760x over previous
//
#include <hip/hip_runtime.h>

typedef __attribute__((ext_vector_type(8))) short bf16x8;
typedef __attribute__((ext_vector_type(4))) float f32x4;
typedef __attribute__((ext_vector_type(4))) int i32x4;

#define Tn 1024
#define Bn 64
#define Hn 2048
#define NBLK 128
#define NTHR 512

// Dataflow ready counters: one line per (consumer-leaf, K-slice-group).
// 16 leaves x 8 groups = 128 counters, each on its own 128B line (16 KB ctrl).
// Replica (leaf, g) is bumped once per step by each of the 16 producer blocks
// of group g (blocks bid>>4 == g); value == 16*(t+1) means h_{t+1}'s slice g
// is fully at MALL. Consumers of leaf L = blocks [8L, 8L+8): wave w polls
// (L, w) only -> 8 pollers/line (R12 lesson: >100 RMW pollers on ONE line
// serialize, so replicate per leaf).
#define GRP(leaf, g) ((((leaf) << 3) | (g)) * 32)

// watchdog: bounded spin so a liveness bug degrades to a wrong answer
// (diagnosable absmax failure) instead of a container-killing hang
#define SPIN_LIMIT (1u << 25)

__device__ __forceinline__ unsigned short f2b(float x) {
    // fp32 -> bf16 round-to-nearest-even
    unsigned u = __float_as_uint(x);
    return (unsigned short)((u + 0x7fffu + ((u >> 16) & 1u)) >> 16);
}
__device__ __forceinline__ float sigm(float x) {
    return __builtin_amdgcn_rcpf(1.0f + __expf(-x));
}
__device__ __forceinline__ float tanh_f(float x) {
    float e = __expf(2.0f * x);
    return 1.0f - 2.0f * __builtin_amdgcn_rcpf(1.0f + e);
}

// write-through system-scope stores: at MALL once vmcnt retires
__device__ __forceinline__ void store_short_wt(unsigned short* p, unsigned v) {
    asm volatile("global_store_short %0, %1, off sc0 sc1" :: "v"(p), "v"(v) : "memory");
}
__device__ __forceinline__ void store_dword_wt(float* p, float v) {
    asm volatile("global_store_dword %0, %1, off sc0 sc1" :: "v"(p), "v"(__float_as_uint(v)) : "memory");
}
__device__ __forceinline__ void store_u64_wt(unsigned long long* p, unsigned long long v) {
    asm volatile("global_store_dwordx2 %0, %1, off sc0 sc1" :: "v"(p), "v"(v) : "memory");
}
// Poll via atomic RMW(+0): the ONLY read primitive proven promptly coherent
// cross-XCD for ATOMICALLY-updated lines (R1-R6 ablation). asm because
// InstCombine turns fetch_add(p,0) back into a plain atomic load.
__device__ __forceinline__ unsigned poll_read(unsigned* p) {
    unsigned old;
    asm volatile("global_atomic_add %0, %1, %2, off sc0 sc1\n\ts_waitcnt vmcnt(0)"
                 : "=v"(old) : "v"(p), "v"(0u) : "memory");
    return old;
}

// h fragment layout: h_f[kk][mt][laneF][e], kk=k>>5, mt=b>>4,
// laneF=((k>>3)&3)*16+(b&15), e=k&7. One MFMA A-frag = 64 lanes x 16B contig.
__device__ __forceinline__ long hfrag_off(int b, int k) {
    return ((long)(((k >> 5) * 4 + (b >> 4)) * 64) + ((k >> 3) & 3) * 16 + (b & 15)) * 8 + (k & 7);
}

// Prep: init_hidden fp32 -> bf16 h0 (frag layout, WT stores so the MALL copy
// is authoritative for gru's bypass loads); zero ready counters (WT too).
__global__ void prep_kernel(const float* __restrict__ init_h,
                            unsigned short* __restrict__ h0,
                            unsigned* __restrict__ ctrl) {
    const int i = blockIdx.x * 256 + threadIdx.x;  // 0..32767
    const int b  = i >> 9;
    const int k4 = (i & 511) << 2;
    float4 v = *reinterpret_cast<const float4*>(init_h + (long)b * Hn + k4);
    unsigned long long q = (unsigned long long)f2b(v.x)
                         | ((unsigned long long)f2b(v.y) << 16)
                         | ((unsigned long long)f2b(v.z) << 32)
                         | ((unsigned long long)f2b(v.w) << 48);
    store_u64_wt((unsigned long long*)(h0 + hfrag_off(b, k4)), q);
    if (i < 4096)
        asm volatile("global_store_dword %0, %1, off sc0 sc1"
                     :: "v"(ctrl + i), "v"(0u) : "memory");
}

// Persistent GRU. 128 blocks x 512 threads (8 waves).
// Block bk owns 16 hidden units j in [16*bk, 16*bk+16).
// Wave w owns K-slice [256w, 256w+256); W rows live in REGISTERS (Bf[3][8]).
//
// R13 (this structure): per-K-slice dataflow flags replaced the grid tree
// barrier (-11%, 5565us). R14 post-mortem (REVERTED here, 7723us):
//  - moving the x loads after the MFMAs put cold inp RTT on the
//    sync4->bump producer path. R13's placement (before the poll) is
//    latency-OPTIMAL: the x RTT hides entirely under the poll's own
//    atomic RTT. DO NOT MOVE.
//  - merging the round-1 add with the round-2 writeback serialized 12
//    dependent ds_read->add->ds_write chains (~0.7us/step); the sync2
//    barrier it saved costs ~10x less. Batched-read/batched-write with
//    barriers between IS the fast form. DO NOT MERGE.
// Both sat on the cross-block ring critical path, so they added ~fully to
// the global period (+2.2us/step).
//
// R15 adds: s_setprio(1) around the MFMA clusters (T5). Regime check: our
// 8 waves are role-diverse at MFMA time (pollers spinning on RMWs, loaders,
// reducers) -> scheduler has something to arbitrate, the attn-like case
// (+4-7%), not the lockstep-GEMM null case.
//
// Buffer-reuse safety (R13): a block stores h_{t+2} only after its 8 waves
// saw all counters at 16(t+1), i.e. after EVERY block stored h_{t+1}, which
// (program order + drain) is after that block finished READING h_t -> the
// double buffer never races. Skew < 2 steps, deadlock-free.
//
// K-loop: 2 ASM-PINNED bursts of 16x global_load_dwordx4 sc0/sc1, each
// followed by a single s_waitcnt vmcnt(0) carrying the 16 buffers as "+v"
// operands (dataflow ties the MFMAs to the waitcnt -> no hoist hazard).
// NOTE: merging the bursts (one fewer serial MALL RTT, ~0.3us/step) needs
// +64 live buffer VGPRs; VGPR(128)+AGPR(<=128) may sit AT the 256/wave
// cliff for 2 waves/SIMD -> spill risk in the hot loop. Deferred until a
// round can afford the gamble.
// TWO-ROUND LDS reduction (48 KB; >64 KB static LDS kills launch, R7/R8).
// NO fences / NO cache maintenance anywhere in the hot loop (R5 lesson).
// All signals via RMW, all polls via RMW(+0).
__global__ void __launch_bounds__(NTHR, 2) gru_kernel(
    const float* __restrict__ inp,     // [T][B][3]
    const float* __restrict__ init_h,  // [B][H]
    const float* __restrict__ w_ih,    // [3H][3]
    const float* __restrict__ w_hh,    // [3H][H] fp32
    const float* __restrict__ bias,    // [3H]
    const float* __restrict__ bias_n,  // [H]
    unsigned short* __restrict__ h0,   // [B][H] bf16 frag-layout double buffer
    unsigned short* __restrict__ h1,
    unsigned* __restrict__ ctrl,       // [4096] ready counters (128 lines)
    float* __restrict__ out)           // [T][B]
{
    __shared__ f32x4 red[4][4][3][64];  // [bucket][mt][nt][lane] = 48 KB

    const int tid  = threadIdx.x;
    const int lane = tid & 63;
    const int w    = tid >> 6;      // wave id = K-slice owner
    const int quad = lane >> 4;
    const int n16  = lane & 15;
    const int j0   = blockIdx.x * 16;
    const int jg   = j0 + n16;      // this lane's hidden column (epilogue)
    const int ks   = w * 256;

    // ---- preload W rows into registers as bf16 B-fragments (one-time) ----
    bf16x8 Bf[3][8];
    #pragma unroll
    for (int nt = 0; nt < 3; ++nt) {
        const long row = (long)(nt * Hn + j0 + n16);
        #pragma unroll
        for (int k = 0; k < 8; ++k) {
            const float* p = w_hh + row * Hn + ks + k * 32 + quad * 8;
            bf16x8 b;
            #pragma unroll
            for (int j = 0; j < 8; ++j) b[j] = (short)f2b(p[j]);
            Bf[nt][k] = b;
        }
    }

    // Epilogue constants (used by waves 0-3; all 64 lanes active)
    float wr0 = w_ih[jg*3+0], wr1 = w_ih[jg*3+1], wr2 = w_ih[jg*3+2];
    float wz0 = w_ih[(Hn+jg)*3+0], wz1 = w_ih[(Hn+jg)*3+1], wz2 = w_ih[(Hn+jg)*3+2];
    float wn0 = w_ih[(2*Hn+jg)*3+0], wn1 = w_ih[(2*Hn+jg)*3+1], wn2 = w_ih[(2*Hn+jg)*3+2];
    float br_ = bias[jg], bz_ = bias[Hn+jg], bn2_ = bias[2*Hn+jg];
    float bnn_ = bias_n[jg];

    // fp32 hidden state (waves 0-3; batch b = 16*w + quad*4 + r, col jg)
    float hst[4];
    if (w < 4) {
        #pragma unroll
        for (int r = 0; r < 4; ++r)
            hst[r] = init_h[(long)(16 * w + quad * 4 + r) * Hn + jg];
    }

    // epilogue frag-store decomposition of j = 16*bid + n16
    const int kkE = blockIdx.x >> 1;            // j>>5 (lane-uniform)
    const int qE  = (blockIdx.x & 1) * 2 + (n16 >> 3);
    const int eE  = n16 & 7;

    const int leafC = blockIdx.x >> 3;          // consumer replica index
    const int grp   = blockIdx.x >> 4;          // K-slice group we produce

    for (int t = 0; t < Tn; ++t) {
        const unsigned short* hcur = (t & 1) ? h1 : h0;
        unsigned short* hnext      = (t & 1) ? h0 : h1;

        // input contributions for this step. Issued BEFORE the poll: their
        // HBM/MALL RTT hides entirely under the poll's own atomic RTT
        // (R14 lesson: any other placement puts them on the critical path).
        float xv[4][3];
        if (w < 4) {
            #pragma unroll
            for (int r = 0; r < 4; ++r) {
                const float* xp = inp + ((long)t * Bn + 16 * w + quad * 4 + r) * 3;
                xv[r][0] = xp[0]; xv[r][1] = xp[1]; xv[r][2] = xp[2];
            }
        }

        f32x4 acc[4][3];
        #pragma unroll
        for (int mt = 0; mt < 4; ++mt)
            #pragma unroll
            for (int nt = 0; nt < 3; ++nt)
                acc[mt][nt] = f32x4{0.f, 0.f, 0.f, 0.f};

        // ---- dataflow wait: THIS wave's K-slice fully at MALL? ----
        // lane 0 spins, wave reconverges; volatile-asm ordering keeps the
        // h-burst loads below from hoisting above the poll.
        if (lane == 0 && t) {
            const unsigned tgt = (unsigned)(t << 4);   // 16*t
            unsigned spins = 0;
            while (poll_read(&ctrl[GRP(leafC, w)]) < tgt) {
                __builtin_amdgcn_s_sleep(1);
                if (++spins > SPIN_LIMIT) break;   // watchdog
            }
        }

        // wave's A-frag base: frag f=(k*4+mt) at short-offset f*512 + lane*8
        const unsigned short* pa = hcur + (long)(w * 8 * 4 * 64 + lane) * 8;

        // ---- 2 asm-pinned bursts: 16x dwordx4 loads, waitcnt, 48 MFMAs ----
        i32x4 hb[16];
        #pragma unroll
        for (int half = 0; half < 2; ++half) {
            const unsigned short* ph = pa + (long)(half * 16) * 512;
            #pragma unroll
            for (int f = 0; f < 16; ++f) {
                asm volatile("global_load_dwordx4 %0, %1, off sc0 sc1"
                             : "=v"(hb[f]) : "v"(ph + (long)f * 512) : "memory");
            }
            asm volatile("s_waitcnt vmcnt(0)"
                         : "+v"(hb[0]), "+v"(hb[1]), "+v"(hb[2]), "+v"(hb[3]),
                           "+v"(hb[4]), "+v"(hb[5]), "+v"(hb[6]), "+v"(hb[7]),
                           "+v"(hb[8]), "+v"(hb[9]), "+v"(hb[10]), "+v"(hb[11]),
                           "+v"(hb[12]), "+v"(hb[13]), "+v"(hb[14]), "+v"(hb[15])
                         :: "memory");
            // T5: prioritize the MFMA-issuing wave over co-resident waves
            // that are spinning in polls / issuing loads.
            __builtin_amdgcn_s_setprio(1);
            #pragma unroll
            for (int k4i = 0; k4i < 4; ++k4i) {
                const int k = half * 4 + k4i;
                #pragma unroll
                for (int mt = 0; mt < 4; ++mt) {
                    union { i32x4 q; bf16x8 v; } u;
                    u.q = hb[k4i * 4 + mt];
                    bf16x8 a = u.v;
                    acc[mt][0] = __builtin_amdgcn_mfma_f32_16x16x32_bf16(a, Bf[0][k], acc[mt][0], 0, 0, 0);
                    acc[mt][1] = __builtin_amdgcn_mfma_f32_16x16x32_bf16(a, Bf[1][k], acc[mt][1], 0, 0, 0);
                    acc[mt][2] = __builtin_amdgcn_mfma_f32_16x16x32_bf16(a, Bf[2][k], acc[mt][2], 0, 0, 0);
                }
            }
            __builtin_amdgcn_s_setprio(0);
        }

        // ---- two-round cross-wave K reduction through LDS (48 KB) ----
        // Batched writes / batched reads with barriers between (R14 lesson:
        // merging read+writeback serializes 12 LDS round-trips).
        if (w >= 4) {
            #pragma unroll
            for (int mt = 0; mt < 4; ++mt)
                #pragma unroll
                for (int nt = 0; nt < 3; ++nt)
                    red[w - 4][mt][nt][lane] = acc[mt][nt];
        }
        __syncthreads();   // sync1
        if (w < 4) {
            #pragma unroll
            for (int mt = 0; mt < 4; ++mt)
                #pragma unroll
                for (int nt = 0; nt < 3; ++nt)
                    acc[mt][nt] += red[w][mt][nt][lane];
        }
        __syncthreads();   // sync2
        if (w < 4) {
            #pragma unroll
            for (int mt = 0; mt < 4; ++mt)
                #pragma unroll
                for (int nt = 0; nt < 3; ++nt)
                    red[w][mt][nt][lane] = acc[mt][nt];
        }
        __syncthreads();   // sync3

        if (w < 4) {
            f32x4 s0 = red[0][w][0][lane], s1 = red[0][w][1][lane], s2 = red[0][w][2][lane];
            #pragma unroll
            for (int src = 1; src < 4; ++src) {
                s0 += red[src][w][0][lane];
                s1 += red[src][w][1][lane];
                s2 += red[src][w][2][lane];
            }
            #pragma unroll
            for (int r = 0; r < 4; ++r) {
                const int b = 16 * w + quad * 4 + r;
                float pr = br_ + wr0*xv[r][0] + wr1*xv[r][1] + wr2*xv[r][2] + s0[r];
                float pz = bz_ + wz0*xv[r][0] + wz1*xv[r][1] + wz2*xv[r][2] + s1[r];
                float rr = sigm(pr);
                float zz = sigm(pz);
                float pn = bn2_ + wn0*xv[r][0] + wn1*xv[r][1] + wn2*xv[r][2] + rr * (s2[r] + bnn_);
                float nn = tanh_f(pn);
                float hv = nn + zz * (hst[r] - nn);
                hst[r] = hv;
                store_short_wt(hnext + ((long)((kkE * 4 + w) * 64) + qE * 16 + quad * 4 + r) * 8 + eE,
                               (unsigned)f2b(hv));
                if (blockIdx.x == 0 && n16 == 0)
                    store_dword_wt(out + t * Bn + b, hv);
            }
        }

        // ---- producer signal: drain WT stores, then bump all 16 leaf
        // replicas of our group's counter (16 lanes, one atomic instr,
        // 16 distinct lines -> no single-line arrival serialization) ----
        asm volatile("s_waitcnt vmcnt(0)" ::: "memory");  // belt-and-braces drain
        __syncthreads();   // sync4: all waves' stores at MALL; fences LDS reuse
        if (tid < 16)
            __hip_atomic_fetch_add(&ctrl[GRP(tid, grp)], 1u,
                                   __ATOMIC_RELAXED, __HIP_MEMORY_SCOPE_SYSTEM);
        // no loop-end barrier: sync4 already orders round-2 reads before any
        // next-iteration LDS write; waves 1-7 head straight into their polls.
    }
}

extern "C" void kernel_launch(void* const* d_in, const int* in_sizes, int n_in,
                              void* d_out, int out_size, void* d_ws, size_t ws_size,
                              hipStream_t stream) {
    const float* inp    = (const float*)d_in[0];  // [1024][64][3]
    const float* init_h = (const float*)d_in[1];  // [64][2048]
    const float* w_ih   = (const float*)d_in[2];  // [6144][3]
    const float* w_hh   = (const float*)d_in[3];  // [6144][2048]
    const float* bias   = (const float*)d_in[4];  // [6144]
    const float* bias_n = (const float*)d_in[5];  // [2048]
    float* out = (float*)d_out;                   // [1024][64]

    unsigned short* h0 = (unsigned short*)d_ws;          // 262144 B
    unsigned short* h1 = h0 + 131072L;                   // 262144 B
    unsigned* ctrl     = (unsigned*)(h1 + 131072L);      // 16384 B

    prep_kernel<<<128, 256, 0, stream>>>(init_h, h0, ctrl);
    gru_kernel<<<NBLK, NTHR, 0, stream>>>(inp, init_h, w_ih, w_hh, bias, bias_n,
                                          h0, h1, ctrl, out);
}

// Round 4
// 4336.965 us; speedup vs baseline: 1.7807x; 1.2941x over previous
//
#include <hip/hip_runtime.h>

typedef __attribute__((ext_vector_type(8))) short bf16x8;
typedef __attribute__((ext_vector_type(4))) float f32x4;
typedef __attribute__((ext_vector_type(4))) int i32x4;

#define Tn 1024
#define Bn 64
#define Hn 2048
#define NBLK 256
#define NTHR 512

// R16: TWO independent rings (batch rows never mix in a GRU). Ring R owns
// batch rows [32R, 32R+32); within a ring, 128 col-blocks as before.
// blockIdx.x -> R = bid & 1, c = bid >> 1 (rings interleave across XCDs).
//
// Dataflow ready counters: one line per (ring, consumer-leaf, K-slice-group).
// 2 rings x 16 leaves x 8 groups = 256 counters, each on its own 128B line
// (32 KB ctrl). Replica (R, leaf, g) is bumped once per step by each of the
// 16 producer col-blocks of group g in ring R (c>>4 == g); value == 16*(t+1)
// means ring R's h_{t+1} slice g is fully at MALL. Consumers: wave w of
// col-block c polls (R, c>>3, w) -> 8 pollers/line (R12 lesson: >100 RMW
// pollers on ONE line serialize, so replicate per leaf).
#define GRP(ring, leaf, g) (((((ring) << 7) | ((leaf) << 3) | (g))) * 32)

// watchdog: bounded spin so a liveness bug degrades to a wrong answer
// (diagnosable absmax failure) instead of a container-killing hang
#define SPIN_LIMIT (1u << 25)

__device__ __forceinline__ unsigned short f2b(float x) {
    // fp32 -> bf16 round-to-nearest-even
    unsigned u = __float_as_uint(x);
    return (unsigned short)((u + 0x7fffu + ((u >> 16) & 1u)) >> 16);
}
__device__ __forceinline__ float sigm(float x) {
    return __builtin_amdgcn_rcpf(1.0f + __expf(-x));
}
__device__ __forceinline__ float tanh_f(float x) {
    float e = __expf(2.0f * x);
    return 1.0f - 2.0f * __builtin_amdgcn_rcpf(1.0f + e);
}

// write-through system-scope stores: at MALL once vmcnt retires
__device__ __forceinline__ void store_short_wt(unsigned short* p, unsigned v) {
    asm volatile("global_store_short %0, %1, off sc0 sc1" :: "v"(p), "v"(v) : "memory");
}
__device__ __forceinline__ void store_dword_wt(float* p, float v) {
    asm volatile("global_store_dword %0, %1, off sc0 sc1" :: "v"(p), "v"(__float_as_uint(v)) : "memory");
}
__device__ __forceinline__ void store_u64_wt(unsigned long long* p, unsigned long long v) {
    asm volatile("global_store_dwordx2 %0, %1, off sc0 sc1" :: "v"(p), "v"(v) : "memory");
}
// Poll via atomic RMW(+0): the ONLY read primitive proven promptly coherent
// cross-XCD for ATOMICALLY-updated lines (R1-R6 ablation). asm because
// InstCombine turns fetch_add(p,0) back into a plain atomic load.
__device__ __forceinline__ unsigned poll_read(unsigned* p) {
    unsigned old;
    asm volatile("global_atomic_add %0, %1, %2, off sc0 sc1\n\ts_waitcnt vmcnt(0)"
                 : "=v"(old) : "v"(p), "v"(0u) : "memory");
    return old;
}

// h fragment layout (GLOBAL, shared by both rings; each ring touches only its
// own mt stripes): h_f[kk][mt][laneF][e], kk=k>>5, mt=b>>4,
// laneF=((k>>3)&3)*16+(b&15), e=k&7. One MFMA A-frag = 64 lanes x 16B contig.
__device__ __forceinline__ long hfrag_off(int b, int k) {
    return ((long)(((k >> 5) * 4 + (b >> 4)) * 64) + ((k >> 3) & 3) * 16 + (b & 15)) * 8 + (k & 7);
}

// Prep: init_hidden fp32 -> bf16 h0 (frag layout, WT stores so the MALL copy
// is authoritative for gru's bypass loads); zero ready counters (WT too).
__global__ void prep_kernel(const float* __restrict__ init_h,
                            unsigned short* __restrict__ h0,
                            unsigned* __restrict__ ctrl) {
    const int i = blockIdx.x * 256 + threadIdx.x;  // 0..32767
    const int b  = i >> 9;
    const int k4 = (i & 511) << 2;
    float4 v = *reinterpret_cast<const float4*>(init_h + (long)b * Hn + k4);
    unsigned long long q = (unsigned long long)f2b(v.x)
                         | ((unsigned long long)f2b(v.y) << 16)
                         | ((unsigned long long)f2b(v.z) << 32)
                         | ((unsigned long long)f2b(v.w) << 48);
    store_u64_wt((unsigned long long*)(h0 + hfrag_off(b, k4)), q);
    if (i < 8192)
        asm volatile("global_store_dword %0, %1, off sc0 sc1"
                     :: "v"(ctrl + i), "v"(0u) : "memory");
}

// Persistent GRU. 256 blocks x 512 threads (8 waves) = 1 block/CU, all CUs.
// Ring R (bid&1) owns batch rows [32R,32R+32); col-block c (bid>>1) owns 16
// hidden units j in [16c, 16c+16). Wave w owns K-slice [256w, 256w+256);
// W rows live in REGISTERS (Bf[3][8]).
//
// R13: per-K-slice dataflow flags replaced the grid tree barrier (-11%).
// R14 (REVERTED): x loads must stay BEFORE the poll (RTT hides under the
//   poll's own atomic RTT); LDS reduce must stay batched-read / batched-write
//   with barriers (merging per-element serializes 12 LDS round-trips).
// R15: setprio around MFMAs — null (short MFMA cluster), kept as harmless.
// R16 (this): batch-split into 2 independent rings. Per-wave A-data halves
//   -> ONE 16-load burst instead of two -> the exposed burst-2 MALL RTT
//   (~0.3-0.4us/step) leaves the ring's critical cycle. MFMA 96->48/wave,
//   LDS 48->24KB, all 256 CUs busy.
//
// Co-residency/liveness: 1 block/CU (8 waves = 2/SIMD; regs<=256/wave;
// 24KB LDS) -> all 256 blocks resident -> rings progress; watchdog bounds
// any bug to a wrong answer instead of a hang.
//
// Buffer-reuse safety (per ring, unchanged logic): a block stores h_{t+2}
// only after its 8 waves saw all its ring's counters at 16(t+1), i.e. after
// EVERY producer of its ring stored h_{t+1}, which (program order + drain)
// is after those blocks finished READING h_t -> the double buffer never
// races. Skew < 2 steps, deadlock-free. Rings are mutually independent
// (disjoint mt stripes, disjoint ctrl lines).
//
// K-loop: 1 ASM-PINNED burst of 16x global_load_dwordx4 sc0/sc1 followed by
// a single s_waitcnt vmcnt(0) carrying the 16 buffers as "+v" operands
// (dataflow ties the MFMAs to the waitcnt -> no hoist hazard).
// TWO-ROUND LDS reduction (24 KB). NO fences / cache maintenance in the hot
// loop (R5). All signals via RMW, all polls via RMW(+0).
__global__ void __launch_bounds__(NTHR, 2) gru_kernel(
    const float* __restrict__ inp,     // [T][B][3]
    const float* __restrict__ init_h,  // [B][H]
    const float* __restrict__ w_ih,    // [3H][3]
    const float* __restrict__ w_hh,    // [3H][H] fp32
    const float* __restrict__ bias,    // [3H]
    const float* __restrict__ bias_n,  // [H]
    unsigned short* __restrict__ h0,   // [B][H] bf16 frag-layout double buffer
    unsigned short* __restrict__ h1,
    unsigned* __restrict__ ctrl,       // [8192] ready counters (256 lines)
    float* __restrict__ out)           // [T][B]
{
    __shared__ f32x4 red[4][2][3][64];  // [bucket][m][nt][lane] = 24 KB

    const int tid  = threadIdx.x;
    const int lane = tid & 63;
    const int w    = tid >> 6;      // wave id = K-slice owner
    const int quad = lane >> 4;
    const int n16  = lane & 15;
    const int R    = blockIdx.x & 1;        // ring id (batch half)
    const int c    = blockIdx.x >> 1;       // col-block id 0..127
    const int j0   = c * 16;
    const int jg   = j0 + n16;      // this lane's hidden column (epilogue)
    const int ks   = w * 256;
    const int bbase = 32 * R;       // ring's batch base

    // ---- preload W rows into registers as bf16 B-fragments (one-time) ----
    bf16x8 Bf[3][8];
    #pragma unroll
    for (int nt = 0; nt < 3; ++nt) {
        const long row = (long)(nt * Hn + jg);
        #pragma unroll
        for (int k = 0; k < 8; ++k) {
            const float* p = w_hh + row * Hn + ks + k * 32 + quad * 8;
            bf16x8 b;
            #pragma unroll
            for (int j = 0; j < 8; ++j) b[j] = (short)f2b(p[j]);
            Bf[nt][k] = b;
        }
    }

    // Epilogue constants (used by waves 0-1; all 64 lanes active)
    float wr0 = w_ih[jg*3+0], wr1 = w_ih[jg*3+1], wr2 = w_ih[jg*3+2];
    float wz0 = w_ih[(Hn+jg)*3+0], wz1 = w_ih[(Hn+jg)*3+1], wz2 = w_ih[(Hn+jg)*3+2];
    float wn0 = w_ih[(2*Hn+jg)*3+0], wn1 = w_ih[(2*Hn+jg)*3+1], wn2 = w_ih[(2*Hn+jg)*3+2];
    float br_ = bias[jg], bz_ = bias[Hn+jg], bn2_ = bias[2*Hn+jg];
    float bnn_ = bias_n[jg];

    // fp32 hidden state (waves 0-1; batch b = bbase + 16w + quad*4 + r, col jg)
    float hst[4];
    if (w < 2) {
        #pragma unroll
        for (int r = 0; r < 4; ++r)
            hst[r] = init_h[(long)(bbase + 16 * w + quad * 4 + r) * Hn + jg];
    }

    // epilogue frag-store decomposition of j = 16c + n16 (mt = 2R + w)
    const int kkE = c >> 1;                     // j>>5 (lane-uniform)
    const int qE  = (c & 1) * 2 + (n16 >> 3);
    const int eE  = n16 & 7;

    const int leafC = c >> 3;          // consumer replica index (per ring)
    const int grp   = c >> 4;          // K-slice group we produce (per ring)

    for (int t = 0; t < Tn; ++t) {
        const unsigned short* hcur = (t & 1) ? h1 : h0;
        unsigned short* hnext      = (t & 1) ? h0 : h1;

        // input contributions for this step. Issued BEFORE the poll: their
        // HBM/MALL RTT hides entirely under the poll's own atomic RTT
        // (R14 lesson: any other placement puts them on the critical path).
        float xv[4][3];
        if (w < 2) {
            #pragma unroll
            for (int r = 0; r < 4; ++r) {
                const float* xp = inp + ((long)t * Bn + bbase + 16 * w + quad * 4 + r) * 3;
                xv[r][0] = xp[0]; xv[r][1] = xp[1]; xv[r][2] = xp[2];
            }
        }

        f32x4 acc[2][3];
        #pragma unroll
        for (int m = 0; m < 2; ++m)
            #pragma unroll
            for (int nt = 0; nt < 3; ++nt)
                acc[m][nt] = f32x4{0.f, 0.f, 0.f, 0.f};

        // ---- dataflow wait: THIS wave's K-slice (this ring) at MALL? ----
        // lane 0 spins, wave reconverges; volatile-asm ordering keeps the
        // h-burst loads below from hoisting above the poll.
        if (lane == 0 && t) {
            const unsigned tgt = (unsigned)(t << 4);   // 16*t
            unsigned spins = 0;
            while (poll_read(&ctrl[GRP(R, leafC, w)]) < tgt) {
                __builtin_amdgcn_s_sleep(1);
                if (++spins > SPIN_LIMIT) break;   // watchdog
            }
        }

        // wave's A-frag base: frag f = 32w + 4*kki + 2R + m, at short-offset
        // f*512 + lane*8 (this ring's two mt stripes of the wave's kk range)
        const unsigned short* pa = hcur + ((long)(32 * w + 2 * R) * 64 + lane) * 8;

        // ---- 1 asm-pinned burst: 16x dwordx4 loads, waitcnt, 48 MFMAs ----
        i32x4 hb[16];
        #pragma unroll
        for (int kki = 0; kki < 8; ++kki) {
            #pragma unroll
            for (int m = 0; m < 2; ++m) {
                asm volatile("global_load_dwordx4 %0, %1, off sc0 sc1"
                             : "=v"(hb[kki * 2 + m])
                             : "v"(pa + (long)(kki * 4 + m) * 512) : "memory");
            }
        }
        asm volatile("s_waitcnt vmcnt(0)"
                     : "+v"(hb[0]), "+v"(hb[1]), "+v"(hb[2]), "+v"(hb[3]),
                       "+v"(hb[4]), "+v"(hb[5]), "+v"(hb[6]), "+v"(hb[7]),
                       "+v"(hb[8]), "+v"(hb[9]), "+v"(hb[10]), "+v"(hb[11]),
                       "+v"(hb[12]), "+v"(hb[13]), "+v"(hb[14]), "+v"(hb[15])
                     :: "memory");
        // T5: prioritize the MFMA-issuing wave over co-resident waves that
        // are spinning in polls / issuing loads (kept from R15; noise-level).
        __builtin_amdgcn_s_setprio(1);
        #pragma unroll
        for (int kki = 0; kki < 8; ++kki) {
            #pragma unroll
            for (int m = 0; m < 2; ++m) {
                union { i32x4 q; bf16x8 v; } u;
                u.q = hb[kki * 2 + m];
                bf16x8 a = u.v;
                acc[m][0] = __builtin_amdgcn_mfma_f32_16x16x32_bf16(a, Bf[0][kki], acc[m][0], 0, 0, 0);
                acc[m][1] = __builtin_amdgcn_mfma_f32_16x16x32_bf16(a, Bf[1][kki], acc[m][1], 0, 0, 0);
                acc[m][2] = __builtin_amdgcn_mfma_f32_16x16x32_bf16(a, Bf[2][kki], acc[m][2], 0, 0, 0);
            }
        }
        __builtin_amdgcn_s_setprio(0);

        // ---- two-round cross-wave K reduction through LDS (24 KB) ----
        // Batched writes / batched reads with barriers between (R14 lesson:
        // merging read+writeback serializes the LDS round-trips).
        if (w >= 4) {
            #pragma unroll
            for (int m = 0; m < 2; ++m)
                #pragma unroll
                for (int nt = 0; nt < 3; ++nt)
                    red[w - 4][m][nt][lane] = acc[m][nt];
        }
        __syncthreads();   // sync1
        if (w < 4) {
            #pragma unroll
            for (int m = 0; m < 2; ++m)
                #pragma unroll
                for (int nt = 0; nt < 3; ++nt)
                    acc[m][nt] += red[w][m][nt][lane];
        }
        __syncthreads();   // sync2
        if (w < 4) {
            #pragma unroll
            for (int m = 0; m < 2; ++m)
                #pragma unroll
                for (int nt = 0; nt < 3; ++nt)
                    red[w][m][nt][lane] = acc[m][nt];
        }
        __syncthreads();   // sync3

        if (w < 2) {
            f32x4 s0 = red[0][w][0][lane], s1 = red[0][w][1][lane], s2 = red[0][w][2][lane];
            #pragma unroll
            for (int src = 1; src < 4; ++src) {
                s0 += red[src][w][0][lane];
                s1 += red[src][w][1][lane];
                s2 += red[src][w][2][lane];
            }
            #pragma unroll
            for (int r = 0; r < 4; ++r) {
                const int b = bbase + 16 * w + quad * 4 + r;
                float pr = br_ + wr0*xv[r][0] + wr1*xv[r][1] + wr2*xv[r][2] + s0[r];
                float pz = bz_ + wz0*xv[r][0] + wz1*xv[r][1] + wz2*xv[r][2] + s1[r];
                float rr = sigm(pr);
                float zz = sigm(pz);
                float pn = bn2_ + wn0*xv[r][0] + wn1*xv[r][1] + wn2*xv[r][2] + rr * (s2[r] + bnn_);
                float nn = tanh_f(pn);
                float hv = nn + zz * (hst[r] - nn);
                hst[r] = hv;
                store_short_wt(hnext + ((long)((kkE * 4 + 2 * R + w) * 64) + qE * 16 + quad * 4 + r) * 8 + eE,
                               (unsigned)f2b(hv));
                if (c == 0 && n16 == 0)
                    store_dword_wt(out + t * Bn + b, hv);
            }
        }

        // ---- producer signal: drain WT stores, then bump all 16 leaf
        // replicas of our ring's group counter (16 lanes, one atomic instr,
        // 16 distinct lines -> no single-line arrival serialization) ----
        asm volatile("s_waitcnt vmcnt(0)" ::: "memory");  // belt-and-braces drain
        __syncthreads();   // sync4: all waves' stores at MALL; fences LDS reuse
        if (tid < 16)
            __hip_atomic_fetch_add(&ctrl[GRP(R, tid, grp)], 1u,
                                   __ATOMIC_RELAXED, __HIP_MEMORY_SCOPE_SYSTEM);
        // no loop-end barrier: sync4 already orders round-2 reads before any
        // next-iteration LDS write; waves 1-7 head straight into their polls.
    }
}

extern "C" void kernel_launch(void* const* d_in, const int* in_sizes, int n_in,
                              void* d_out, int out_size, void* d_ws, size_t ws_size,
                              hipStream_t stream) {
    const float* inp    = (const float*)d_in[0];  // [1024][64][3]
    const float* init_h = (const float*)d_in[1];  // [64][2048]
    const float* w_ih   = (const float*)d_in[2];  // [6144][3]
    const float* w_hh   = (const float*)d_in[3];  // [6144][2048]
    const float* bias   = (const float*)d_in[4];  // [6144]
    const float* bias_n = (const float*)d_in[5];  // [2048]
    float* out = (float*)d_out;                   // [1024][64]

    unsigned short* h0 = (unsigned short*)d_ws;          // 262144 B
    unsigned short* h1 = h0 + 131072L;                   // 262144 B
    unsigned* ctrl     = (unsigned*)(h1 + 131072L);      // 32768 B

    prep_kernel<<<128, 256, 0, stream>>>(init_h, h0, ctrl);
    gru_kernel<<<NBLK, NTHR, 0, stream>>>(inp, init_h, w_ih, w_hh, bias, bias_n,
                                          h0, h1, ctrl, out);
}